// Round 1
// baseline (275.305 us; speedup 1.0000x reference)
//
#include <hip/hip_runtime.h>
#include <hip/hip_bf16.h>

// Problem constants: B=4, C=512, H=W=64 -> N=4096, CK=64
#define NB 4
#define CC 512
#define NN 4096
#define CKK 64

typedef _Float16 f16x8 __attribute__((ext_vector_type(8)));
typedef float    f32x4 __attribute__((ext_vector_type(4)));

// ---------------------------------------------------------------------------
// async global->LDS, 16 B per lane. LDS dest is wave-uniform base + lane*16.
// ---------------------------------------------------------------------------
__device__ __forceinline__ void g2l16(const _Float16* g, _Float16* l) {
    __builtin_amdgcn_global_load_lds(
        (const __attribute__((address_space(1))) void*)g,
        (__attribute__((address_space(3))) void*)l, 16, 0, 0);
}

// Stage a 128-row x 32-col f16 tile (row stride ldg) into LDS [128][32],
// 256 threads (4 waves). Linear layout (used by proj).
__device__ __forceinline__ void stage_tile(const _Float16* __restrict__ g, int ldg,
                                           _Float16* lds, int lane, int wave) {
    #pragma unroll
    for (int r = 0; r < 2; r++) {
        int q = r * 4 + wave;
        int row = q * 16 + (lane >> 2);
        int col = (lane & 3) * 8;
        g2l16(g + (size_t)row * ldg + col, lds + q * 512 + lane * 8);
    }
}

// Stage a 128x32 f16 tile with 512 threads, ONE g2l16 per thread.
// LDS dest stays linear (required by global_load_lds); the GLOBAL source
// column-chunk is pre-permuted by (row>>1)&3 so the stored layout is
// XOR-swizzled. Readers apply the same involution (rd_swz) -> 8-way
// bank conflicts on fragment reads become 2-way (free).
__device__ __forceinline__ void stage_swz(const _Float16* __restrict__ g, int ldg,
                                          _Float16* lds, int tid) {
    int row = tid >> 2;
    int scq = (tid & 3) ^ ((row >> 1) & 3);
    g2l16(g + (size_t)row * ldg + scq * 8, lds + tid * 8);
}

__device__ __forceinline__ f16x8 rd_swz(const _Float16* lds, int row, int quad) {
    int q = quad ^ ((row >> 1) & 3);
    return *(const f16x8*)(lds + row * 32 + q * 8);
}

// ---------------------------------------------------------------------------
// K0 "prep": blocks 0..2047 transpose x (fp32 [B][C][N]) -> xT (f16 [B][N][C]);
// blocks 2048..2687 pack Wf/Wg/Wh -> Wall[640][512] f16 + Ball[640] fp32.
// ---------------------------------------------------------------------------
__launch_bounds__(256)
__global__ void prep(const float* __restrict__ x, _Float16* __restrict__ xT,
                     const float* __restrict__ Wf, const float* __restrict__ bf_,
                     const float* __restrict__ Wg, const float* __restrict__ bg_,
                     const float* __restrict__ Wh, const float* __restrict__ bh_,
                     _Float16* __restrict__ Wall, float* __restrict__ Ball) {
    const int N = NN, C = CC;
    int bid = blockIdx.x;
    int t = threadIdx.x;
    if (bid < 2048) {
        int n0 = (bid & 63) << 6;
        int c0 = ((bid >> 6) & 7) << 6;
        int b  = bid >> 9;
        __shared__ float T[64][65];
        const float* xb = x + (size_t)b * C * N;
        #pragma unroll
        for (int r = 0; r < 4; r++) {
            int c = (t >> 4) + 16 * r;
            int n4 = (t & 15) * 4;
            float4 v = *(const float4*)(xb + (size_t)(c0 + c) * N + n0 + n4);
            T[n4 + 0][c] = v.x; T[n4 + 1][c] = v.y; T[n4 + 2][c] = v.z; T[n4 + 3][c] = v.w;
        }
        __syncthreads();
        int n = t >> 2, cb = (t & 3) * 16;
        f16x8 h0, h1;
        #pragma unroll
        for (int i = 0; i < 8; i++) { h0[i] = (_Float16)T[n][cb + i]; h1[i] = (_Float16)T[n][cb + 8 + i]; }
        _Float16* dst = xT + (size_t)b * N * C + (size_t)(n0 + n) * C + c0 + cb;
        *(f16x8*)dst = h0;
        *(f16x8*)(dst + 8) = h1;
    } else {
        int o = bid - 2048;  // 0..639
        const float* src;
        if (o < 64)       src = Wf + (size_t)o * C;
        else if (o < 128) src = Wg + (size_t)(o - 64) * C;
        else              src = Wh + (size_t)(o - 128) * C;
        Wall[(size_t)o * C + t]       = (_Float16)src[t];
        Wall[(size_t)o * C + 256 + t] = (_Float16)src[256 + t];
        if (t == 0)
            Ball[o] = (o < 64) ? bf_[o] : (o < 128 ? bg_[o - 64] : bh_[o - 128]);
    }
}

// ---------------------------------------------------------------------------
// K1: projections, NT MFMA GEMM. Y[o][n] = sum_c Wall[o][c]*xT[n][c] + Ball[o]
// ---------------------------------------------------------------------------
__launch_bounds__(256)
__global__ void proj_mfma(const _Float16* __restrict__ xT, const _Float16* __restrict__ Wall,
                          const float* __restrict__ Ball,
                          _Float16* __restrict__ Ft, _Float16* __restrict__ Gt,
                          _Float16* __restrict__ Hx) {
    const int N = NN, C = CC;
    int n0 = blockIdx.x * 128;
    int o0 = blockIdx.y * 128;
    int b  = blockIdx.z;
    const _Float16* Arow = Wall + (size_t)o0 * C;
    const _Float16* Brow = xT + (size_t)b * N * C + (size_t)n0 * C;
    __shared__ _Float16 As[128 * 32];
    __shared__ _Float16 Bs[128 * 32];
    int tid = threadIdx.x, lane = tid & 63, wave = tid >> 6;
    int wm = wave & 1, wn = wave >> 1, lrow = lane & 15, quad = lane >> 4;
    f32x4 acc[4][4] = {};
    for (int kc = 0; kc < C; kc += 32) {
        __syncthreads();
        stage_tile(Arow + kc, C, As, lane, wave);
        stage_tile(Brow + kc, C, Bs, lane, wave);
        __syncthreads();
        f16x8 af[4], bf[4];
        #pragma unroll
        for (int mi = 0; mi < 4; mi++)
            af[mi] = *(const f16x8*)(As + (wm * 64 + mi * 16 + lrow) * 32 + quad * 8);
        #pragma unroll
        for (int ni = 0; ni < 4; ni++)
            bf[ni] = *(const f16x8*)(Bs + (wn * 64 + ni * 16 + lrow) * 32 + quad * 8);
        #pragma unroll
        for (int mi = 0; mi < 4; mi++)
            #pragma unroll
            for (int ni = 0; ni < 4; ni++)
                acc[mi][ni] = __builtin_amdgcn_mfma_f32_16x16x32_f16(af[mi], bf[ni], acc[mi][ni], 0, 0, 0);
    }
    float bias_r[4][4];
    #pragma unroll
    for (int mi = 0; mi < 4; mi++)
        #pragma unroll
        for (int r = 0; r < 4; r++)
            bias_r[mi][r] = Ball[o0 + wm * 64 + mi * 16 + quad * 4 + r];
    _Float16* Ftb = Ft + (size_t)b * NN * CKK;
    _Float16* Gtb = Gt + (size_t)b * NN * CKK;
    _Float16* Hxb = Hx + (size_t)b * CC * N;
    #pragma unroll
    for (int mi = 0; mi < 4; mi++)
        #pragma unroll
        for (int ni = 0; ni < 4; ni++)
            #pragma unroll
            for (int r = 0; r < 4; r++) {
                int o = o0 + wm * 64 + mi * 16 + quad * 4 + r;
                int n = n0 + wn * 64 + ni * 16 + lrow;
                _Float16 v = (_Float16)(acc[mi][ni][r] + bias_r[mi][r]);
                if (o < 64)       Ftb[(size_t)n * CKK + o] = v;
                else if (o < 128) Gtb[(size_t)n * CKK + (o - 64)] = v;
                else              Hxb[(size_t)(o - 128) * N + n] = v;
            }
}

// ---------------------------------------------------------------------------
// K2: fused flash-style attention. Per block: i-tile 128 x c-tile 256.
// Loop over 32 j-tiles: S = Ft_tile . Gt_tile^T (K=64, recomputed per c-half),
// online softmax (running m,l per row in LDS; O-acc rescaled in f32),
// P' = exp(f16(s)-m) staged ONLY through LDS (Pst), PV MFMA vs streamed Hx.
// P never touches HBM. Epilogue: out = gamma*(O/l) + x.
// S-phase waves:  wi=w&3 (i 32-group), wj=w>>2 (j 64-half)
// PV-phase waves: wc=w>>1 (c 64-group), wi2=w&1 (i 64-half)
// ---------------------------------------------------------------------------
#define PST_LD  136   // Pst row stride (f16): (row + 4kk + quad) mod 8 spread -> 2-way
#define MRED_LD 34    // reduction matrix stride (f32): 2-way free both phases
#define SM_FT    0
#define SM_BSG   16384
#define SM_PST   32768
#define SM_AH    67584
#define SM_MRED  100352
#define SM_MRUN  117760
#define SM_LRUN  118272
#define SM_OSC   118784
#define SM_TOTAL 119296

__launch_bounds__(512, 2)
__global__ void attn_fused(const _Float16* __restrict__ Ft, const _Float16* __restrict__ Gt,
                           const _Float16* __restrict__ Hx, const float* __restrict__ x,
                           const float* __restrict__ gamma, float* __restrict__ out) {
    const int N = NN, C = CC;
    extern __shared__ char smem[];
    _Float16* FtL = (_Float16*)(smem + SM_FT);    // [2 ks][128][32] swizzled
    _Float16* BsG = (_Float16*)(smem + SM_BSG);   // [2 ks][128][32] swizzled (Gt tile)
    _Float16* Pst = (_Float16*)(smem + SM_PST);   // [128][PST_LD]
    _Float16* Ah  = (_Float16*)(smem + SM_AH);    // 2 x [256][32] swizzled (Hx chunks)
    float* Mred = (float*)(smem + SM_MRED);       // [128][MRED_LD] reduce partials
    float* Mrun = (float*)(smem + SM_MRUN);       // [128] running row max
    float* Lrun = (float*)(smem + SM_LRUN);       // [128] running row sum
    float* Osc  = (float*)(smem + SM_OSC);        // [128] per-tile rescale / final 1/l

    const int b  = blockIdx.z;
    const int i0 = blockIdx.x * 128;
    const int c0 = blockIdx.y * 256;
    const int tid = threadIdx.x;
    const int lane = tid & 63, w = tid >> 6;
    const int lrow = lane & 15, quad = lane >> 4;
    const int wi = w & 3, wj = w >> 2;
    const int wc = w >> 1, wi2 = w & 1;

    const _Float16* Ftb = Ft + (size_t)b * N * CKK + (size_t)i0 * CKK;
    const _Float16* Gtb = Gt + (size_t)b * N * CKK;
    const _Float16* Hxb = Hx + (size_t)b * C * N + (size_t)c0 * N;

    // prologue: Ft tile [128][64] staged once, fragments held in registers
    stage_swz(Ftb,      CKK, FtL,        tid);
    stage_swz(Ftb + 32, CKK, FtL + 4096, tid);
    if (tid < 128) { Mrun[tid] = -1e30f; Lrun[tid] = 0.0f; }
    __syncthreads();

    f16x8 afs[2][2];
    #pragma unroll
    for (int mi = 0; mi < 2; mi++)
        #pragma unroll
        for (int ks = 0; ks < 2; ks++)
            afs[mi][ks] = rd_swz(FtL + ks * 4096, wi * 32 + mi * 16 + lrow, quad);

    f32x4 acc[4][4] = {};

    for (int jt = 0; jt < NN / 128; jt++) {
        // ---- stage Gt tile for this j-tile ----
        const _Float16* Gtr = Gtb + (size_t)jt * 128 * CKK;
        stage_swz(Gtr,      CKK, BsG,        tid);
        stage_swz(Gtr + 32, CKK, BsG + 4096, tid);
        __syncthreads();                                   // B1: BsG ready

        // ---- S = Ft . Gt^T for this wave's 32i x 64j sub-tile ----
        f32x4 sacc[2][4] = {};
        #pragma unroll
        for (int ks = 0; ks < 2; ks++)
            #pragma unroll
            for (int ni = 0; ni < 4; ni++) {
                f16x8 bfs = rd_swz(BsG + ks * 4096, wj * 64 + ni * 16 + lrow, quad);
                #pragma unroll
                for (int mi = 0; mi < 2; mi++)
                    sacc[mi][ni] = __builtin_amdgcn_mfma_f32_16x16x32_f16(afs[mi][ks], bfs, sacc[mi][ni], 0, 0, 0);
            }
        // ---- row-max partials (max over this thread's 4 ni) -> Mred ----
        #pragma unroll
        for (int mi = 0; mi < 2; mi++)
            #pragma unroll
            for (int r = 0; r < 4; r++) {
                float v = fmaxf(fmaxf(sacc[mi][0][r], sacc[mi][1][r]),
                                fmaxf(sacc[mi][2][r], sacc[mi][3][r]));
                int row = wi * 32 + mi * 16 + quad * 4 + r;
                Mred[row * MRED_LD + wj * 16 + lrow] = v;
            }
        __syncthreads();                                   // B2
        // ---- online stats update (one thread per row) ----
        if (tid < 128) {
            const float* mr = Mred + tid * MRED_LD;
            float mt = mr[0];
            #pragma unroll
            for (int k = 1; k < 32; k++) mt = fmaxf(mt, mr[k]);
            float mo = Mrun[tid];
            float mn = fmaxf(mo, mt);
            float sc = __expf(mo - mn);   // first tile: exp(-inf) = 0
            Mrun[tid] = mn;
            Osc[tid] = sc;
            Lrun[tid] *= sc;
        }
        __syncthreads();                                   // B3
        // ---- P' = exp(f16(s) - m) -> Pst ; lsum partials -> Mred ----
        #pragma unroll
        for (int mi = 0; mi < 2; mi++)
            #pragma unroll
            for (int r = 0; r < 4; r++) {
                int row = wi * 32 + mi * 16 + quad * 4 + r;
                float m = Mrun[row];
                float ls = 0.f;
                #pragma unroll
                for (int ni = 0; ni < 4; ni++) {
                    float s16 = (float)(_Float16)sacc[mi][ni][r];
                    _Float16 p16 = (_Float16)__expf(s16 - m);
                    Pst[row * PST_LD + wj * 64 + ni * 16 + lrow] = p16;
                    ls += (float)p16;
                }
                Mred[row * MRED_LD + wj * 16 + lrow] = ls;
            }
        // ---- rescale O accumulator by exp(m_old - m_new) (f32, exact) ----
        float scv[4];
        #pragma unroll
        for (int ni = 0; ni < 4; ni++) scv[ni] = Osc[wi2 * 64 + ni * 16 + lrow];
        #pragma unroll
        for (int mi = 0; mi < 4; mi++)
            #pragma unroll
            for (int ni = 0; ni < 4; ni++)
                #pragma unroll
                for (int r = 0; r < 4; r++)
                    acc[mi][ni][r] *= scv[ni];
        __syncthreads();                                   // B4: Pst + lsum ready
        if (tid < 128) {
            const float* mr = Mred + tid * MRED_LD;
            float s = 0.f;
            #pragma unroll
            for (int k = 0; k < 32; k++) s += mr[k];
            Lrun[tid] += s;
        }
        // ---- PV: O[c][i] += Hx[c][j] * P'[i][j], 4 k-chunks, Ah dbuf ----
        const _Float16* Hxr = Hxb + (size_t)jt * 128;
        stage_swz(Hxr,                   N, Ah,        tid);
        stage_swz(Hxr + (size_t)128 * N, N, Ah + 4096, tid);
        #pragma unroll
        for (int kk = 0; kk < 4; kk++) {
            if (kk < 3) {
                const _Float16* src = Hxr + (kk + 1) * 32;
                _Float16* dst = Ah + ((kk + 1) & 1) * 8192;
                stage_swz(src,                   N, dst,        tid);
                stage_swz(src + (size_t)128 * N, N, dst + 4096, tid);
            }
            __syncthreads();                               // B5..B8: Ah[kk] ready
            const _Float16* A = Ah + (kk & 1) * 8192;
            f16x8 bfv[4];
            #pragma unroll
            for (int ni = 0; ni < 4; ni++)
                bfv[ni] = *(const f16x8*)(Pst + (wi2 * 64 + ni * 16 + lrow) * PST_LD + kk * 32 + quad * 8);
            #pragma unroll
            for (int mi = 0; mi < 4; mi++) {
                f16x8 av = rd_swz(A, wc * 64 + mi * 16 + lrow, quad);
                #pragma unroll
                for (int ni = 0; ni < 4; ni++)
                    acc[mi][ni] = __builtin_amdgcn_mfma_f32_16x16x32_f16(av, bfv[ni], acc[mi][ni], 0, 0, 0);
            }
        }
    }
    __syncthreads();
    if (tid < 128) Osc[tid] = 1.0f / Lrun[tid];
    __syncthreads();
    float gv = gamma[0];
    const float* xb = x + (size_t)b * C * N;
    float* ob = out + (size_t)b * C * N;
    float li[4];
    #pragma unroll
    for (int ni = 0; ni < 4; ni++) li[ni] = Osc[wi2 * 64 + ni * 16 + lrow];
    #pragma unroll
    for (int mi = 0; mi < 4; mi++)
        #pragma unroll
        for (int ni = 0; ni < 4; ni++)
            #pragma unroll
            for (int r = 0; r < 4; r++) {
                int c = c0 + wc * 64 + mi * 16 + quad * 4 + r;
                int i = i0 + wi2 * 64 + ni * 16 + lrow;
                ob[(size_t)c * N + i] = gv * (acc[mi][ni][r] * li[ni]) + xb[(size_t)c * N + i];
            }
}

extern "C" void kernel_launch(void* const* d_in, const int* in_sizes, int n_in,
                              void* d_out, int out_size, void* d_ws, size_t ws_size,
                              hipStream_t stream) {
    const float* x     = (const float*)d_in[0];
    const float* Wf    = (const float*)d_in[1];
    const float* bf    = (const float*)d_in[2];
    const float* Wg    = (const float*)d_in[3];
    const float* bg    = (const float*)d_in[4];
    const float* Wh    = (const float*)d_in[5];
    const float* bh    = (const float*)d_in[6];
    const float* gamma = (const float*)d_in[7];
    float* out = (float*)d_out;

    // Workspace layout (bytes):
    //   Wall [640][512] f16    @ 0        (640 KiB)
    //   Ball [640]      fp32   @ 768 KiB
    //   Ft   [B][N][64] f16    @ 1 MiB    (2 MiB)
    //   Gt   [B][N][64] f16    @ 3 MiB    (2 MiB)
    //   Hx   [B][C][N]  f16    @ 5 MiB    (16 MiB)
    //   xT   [B][N][C]  f16    @ 21 MiB   (17 MiB)
    //   (P / Mpart / Lpart eliminated — attention fully fused)
    char* wsb = (char*)d_ws;
    _Float16* Wall = (_Float16*)wsb;
    float*    Ball = (float*)(wsb + ((size_t)768 << 10));
    _Float16* Ft = (_Float16*)(wsb + ((size_t)1 << 20));
    _Float16* Gt = (_Float16*)(wsb + ((size_t)3 << 20));
    _Float16* Hx = (_Float16*)(wsb + ((size_t)5 << 20));
    _Float16* xT = (_Float16*)(wsb + ((size_t)21 << 20));

    prep<<<dim3(2048 + 640), dim3(256), 0, stream>>>(
        x, xT, Wf, bf, Wg, bg, Wh, bh, Wall, Ball);
    proj_mfma<<<dim3(NN / 128, 5, NB), dim3(256), 0, stream>>>(xT, Wall, Ball, Ft, Gt, Hx);

    hipFuncSetAttribute((const void*)attn_fused,
                        hipFuncAttributeMaxDynamicSharedMemorySize, SM_TOTAL);
    attn_fused<<<dim3(NN / 128, CC / 256, NB), dim3(512), SM_TOTAL, stream>>>(
        Ft, Gt, Hx, x, gamma, out);
}